// Round 2
// baseline (1228.737 us; speedup 1.0000x reference)
//
#include <hip/hip_runtime.h>
#include <hip/hip_bf16.h>

typedef __attribute__((ext_vector_type(8))) short short8;
typedef __attribute__((ext_vector_type(4))) float f32x4;
typedef unsigned short u16;
typedef unsigned int u32;

#define NODES 16384
#define CHN 128
#define NEDGE 524288
#define NG 16
#define NPGC 1024
#define NHEAD 4
#define HDIM 32
#define NLAYER 4

__device__ __forceinline__ float bf2f(u16 u) {
    union { u32 u; float f; } c; c.u = ((u32)u) << 16; return c.f;
}
__device__ __forceinline__ u16 f2bf(float f) {
    union { float f; u32 u; } c; c.f = f;
    u32 r = c.u + 0x7fffu + ((c.u >> 16) & 1u);
    return (u16)(r >> 16);
}
__device__ __forceinline__ void fsplit(float f, u16& hi, u16& lo) {
    u16 h = f2bf(f);
    hi = h;
    lo = f2bf(f - bf2f(h));
}

#define MFMA16(a, b, c) __builtin_amdgcn_mfma_f32_16x16x32_bf16((a), (b), (c), 0, 0, 0)

__device__ __forceinline__ short8 ld_frag(const u16* p) {
    return *reinterpret_cast<const short8*>(p);
}

// ---------------- setup kernels ----------------

__global__ void k_split(const float* __restrict__ src, u16* __restrict__ hi,
                        u16* __restrict__ lo, int n) {
    int i = blockIdx.x * 256 + threadIdx.x;
    if (i < n) {
        u16 h, l;
        fsplit(src[i], h, l);
        hi[i] = h; lo[i] = l;
    }
}

__global__ void k_bnprep(const float* __restrict__ g, const float* __restrict__ b,
                         const float* __restrict__ m, const float* __restrict__ v,
                         float* __restrict__ scale, float* __restrict__ shift) {
    int i = blockIdx.x * 256 + threadIdx.x;
    if (i < NLAYER * 3 * CHN) {
        float s = g[i] * rsqrtf(v[i] + 1e-5f);
        scale[i] = s;
        shift[i] = b[i] - m[i] * s;
    }
}

__global__ void k_zero_u32(u32* __restrict__ p, int n) {
    int i = blockIdx.x * 256 + threadIdx.x;
    if (i < n) p[i] = 0u;
}

__global__ void k_count(const int* __restrict__ dst, u32* __restrict__ counts) {
    int e = blockIdx.x * 256 + threadIdx.x;
    if (e < NEDGE) atomicAdd(&counts[dst[e]], 1u);
}

// single block, 256 threads, 64 elems each
__global__ void k_scan(const u32* __restrict__ counts, u32* __restrict__ offsets,
                       u32* __restrict__ cursor) {
    __shared__ u32 part[256];
    int t = threadIdx.x;
    int base = t * 64;
    u32 s = 0;
    for (int i = 0; i < 64; ++i) s += counts[base + i];
    part[t] = s;
    __syncthreads();
    for (int off = 1; off < 256; off <<= 1) {
        u32 val = (t >= off) ? part[t - off] : 0u;
        __syncthreads();
        part[t] += val;
        __syncthreads();
    }
    u32 run = (t == 0) ? 0u : part[t - 1];
    for (int i = 0; i < 64; ++i) {
        offsets[base + i] = run;
        cursor[base + i] = run;
        run += counts[base + i];
    }
    if (t == 255) offsets[NODES] = run;
}

__global__ void k_fill(const int* __restrict__ src, const int* __restrict__ dst,
                       const float* __restrict__ eattr, u32* __restrict__ cursor,
                       int* __restrict__ csr_src, float* __restrict__ csr_a) {
    int e = blockIdx.x * 256 + threadIdx.x;
    if (e >= NEDGE) return;
    int d = dst[e];
    u32 p = atomicAdd(&cursor[d], 1u);
    csr_src[p] = src[e];
    csr_a[p] = eattr[e];
}

// -------- GINE aggregation: z1 = h + sum_in relu(h[src] + a*ew + eb), fp32 in, hi/lo out ---

__global__ __launch_bounds__(64) void k_agg(
    const float* __restrict__ h_f32, const u32* __restrict__ offsets,
    const int* __restrict__ csr_src, const float* __restrict__ csr_a,
    const float* __restrict__ ew, const float* __restrict__ eb,
    u16* __restrict__ z_hi, u16* __restrict__ z_lo) {
    int node = blockIdx.x;
    int t = threadIdx.x;          // 64 threads, 2 channels each
    int c0 = t * 2;
    float w0 = ew[c0], w1 = ew[c0 + 1];
    float b0 = eb[c0], b1 = eb[c0 + 1];
    u32 beg = offsets[node], end = offsets[node + 1];
    float acc0 = 0.f, acc1 = 0.f;
    for (u32 j = beg; j < end; ++j) {
        int s = csr_src[j];
        float a = csr_a[j];
        const float* hp = h_f32 + (size_t)s * CHN + c0;
        float f0 = hp[0], f1 = hp[1];
        acc0 += fmaxf(f0 + a * w0 + b0, 0.f);
        acc1 += fmaxf(f1 + a * w1 + b1, 0.f);
    }
    size_t idx = (size_t)node * CHN + c0;
    float z0 = h_f32[idx] + acc0;
    float z1v = h_f32[idx + 1] + acc1;
    u16 h, l;
    fsplit(z0, h, l); z_hi[idx] = h; z_lo[idx] = l;
    fsplit(z1v, h, l); z_hi[idx + 1] = h; z_lo[idx + 1] = l;
}

// ------ split GEMM: acc = (Ah+Al)@(Wh+Wl)^T; epi: +bias; +resid1; *bn+; +resid2; relu ------

__global__ __launch_bounds__(256) void k_gemm(
    const u16* __restrict__ Ahi, const u16* __restrict__ Alo,
    const u16* __restrict__ Whi, const u16* __restrict__ Wlo,
    const float* __restrict__ bias, const float* __restrict__ resid1,
    const float* __restrict__ bnscale, const float* __restrict__ bnshift,
    const float* __restrict__ resid2, float* __restrict__ out_f32,
    u16* __restrict__ out_hi, u16* __restrict__ out_lo, int K, int Nc, int relu) {
    int tid = threadIdx.x;
    int wave = tid >> 6, lane = tid & 63;
    int lr = lane & 15, lg = lane >> 4;
    int r0 = blockIdx.x * 64 + wave * 16;
    int nb = blockIdx.y * 64;
    f32x4 acc[4] = {};
    size_t arow = (size_t)(r0 + lr) * K + lg * 8;
    for (int ks = 0; ks < K; ks += 32) {
        short8 ah = ld_frag(Ahi + arow + ks);
        short8 al = ld_frag(Alo + arow + ks);
#pragma unroll
        for (int n = 0; n < 4; ++n) {
            size_t wrow = (size_t)(nb + n * 16 + lr) * K + ks + lg * 8;
            short8 wh = ld_frag(Whi + wrow);
            short8 wl = ld_frag(Wlo + wrow);
            acc[n] = MFMA16(ah, wh, acc[n]);
            acc[n] = MFMA16(al, wh, acc[n]);
            acc[n] = MFMA16(ah, wl, acc[n]);
        }
    }
#pragma unroll
    for (int n = 0; n < 4; ++n) {
        int col = nb + n * 16 + lr;
        float bs = bias ? bias[col] : 0.f;
        float sc = bnscale ? bnscale[col] : 1.f;
        float sh = bnshift ? bnshift[col] : 0.f;
#pragma unroll
        for (int r = 0; r < 4; ++r) {
            int row = r0 + lg * 4 + r;
            size_t oidx = (size_t)row * Nc + col;
            float v = acc[n][r] + bs;
            if (resid1) v += resid1[oidx];
            v = v * sc + sh;
            if (resid2) v += resid2[oidx];
            if (relu) v = fmaxf(v, 0.f);
            if (out_f32) out_f32[oidx] = v;
            if (out_hi) {
                u16 hh, ll;
                fsplit(v, hh, ll);
                out_hi[oidx] = hh; out_lo[oidx] = ll;
            }
        }
    }
}

// ---------------- QKV GEMM with head-split hi/lo store (V transposed) ----------------

__global__ __launch_bounds__(256) void k_qkv(
    const u16* __restrict__ Ahi, const u16* __restrict__ Alo,
    const u16* __restrict__ Whi, const u16* __restrict__ Wlo,
    const float* __restrict__ bias,
    u16* __restrict__ q_hi, u16* __restrict__ q_lo,
    u16* __restrict__ k_hi, u16* __restrict__ k_lo,
    u16* __restrict__ vt_hi, u16* __restrict__ vt_lo) {
    const int K = 128;
    int tid = threadIdx.x;
    int wave = tid >> 6, lane = tid & 63;
    int lr = lane & 15, lg = lane >> 4;
    int r0 = blockIdx.x * 64 + wave * 16;
    int nb = blockIdx.y * 64;    // grid.y = 6 -> 384 cols
    f32x4 acc[4] = {};
    size_t arow = (size_t)(r0 + lr) * K + lg * 8;
    for (int ks = 0; ks < K; ks += 32) {
        short8 ah = ld_frag(Ahi + arow + ks);
        short8 al = ld_frag(Alo + arow + ks);
#pragma unroll
        for (int n = 0; n < 4; ++n) {
            size_t wrow = (size_t)(nb + n * 16 + lr) * K + ks + lg * 8;
            short8 wh = ld_frag(Whi + wrow);
            short8 wl = ld_frag(Wlo + wrow);
            acc[n] = MFMA16(ah, wh, acc[n]);
            acc[n] = MFMA16(al, wh, acc[n]);
            acc[n] = MFMA16(ah, wl, acc[n]);
        }
    }
#pragma unroll
    for (int n = 0; n < 4; ++n) {
        int col = nb + n * 16 + lr;
        int region = col >> 7;
        int c = col & 127;
        int hh = c >> 5, d = c & 31;
        float bs = bias[col];
#pragma unroll
        for (int r = 0; r < 4; ++r) {
            int row = r0 + lg * 4 + r;
            float v = acc[n][r] + bs;
            u16 vh, vl;
            fsplit(v, vh, vl);
            int g = row >> 10, p = row & 1023;
            size_t gh = (size_t)(g * NHEAD + hh);
            if (region == 0) {
                size_t o = (gh * NPGC + p) * HDIM + d;
                q_hi[o] = vh; q_lo[o] = vl;
            } else if (region == 1) {
                size_t o = (gh * NPGC + p) * HDIM + d;
                k_hi[o] = vh; k_lo[o] = vl;
            } else {
                size_t o = (gh * HDIM + d) * NPGC + p;
                vt_hi[o] = vh; vt_lo[o] = vl;
            }
        }
    }
}

// ------------- flash attention, split precision: 4 waves/block, 16 q-rows/wave -------------

__global__ __launch_bounds__(256) void k_attn(
    const u16* __restrict__ qhi, const u16* __restrict__ qlo,
    const u16* __restrict__ khi, const u16* __restrict__ klo,
    const u16* __restrict__ vthi, const u16* __restrict__ vtlo,
    u16* __restrict__ aohi, u16* __restrict__ aolo) {
    __shared__ __align__(16) u16 plds[4][2][16][40];   // [wave][hi/lo][row][32+pad]
    int tid = threadIdx.x;
    int wave = tid >> 6, lane = tid & 63;
    int lr = lane & 15, lg = lane >> 4;
    int gh = blockIdx.y;                       // g*4 + head
    int q0 = blockIdx.x * 64 + wave * 16;      // row within NPG
    size_t qbase = (size_t)gh * NPGC * HDIM;
    size_t vbase = (size_t)gh * HDIM * NPGC;
    short8 qh = ld_frag(qhi + qbase + (size_t)(q0 + lr) * HDIM + lg * 8);
    short8 ql = ld_frag(qlo + qbase + (size_t)(q0 + lr) * HDIM + lg * 8);
    const u16* Kh = khi + qbase;
    const u16* Kl = klo + qbase;
    const u16* Vh = vthi + vbase;
    const u16* Vl = vtlo + vbase;
    f32x4 o0 = {}, o1 = {};
    float m[4], l[4];
#pragma unroll
    for (int r = 0; r < 4; ++r) { m[r] = -1e30f; l[r] = 0.f; }
    const float scale = 0.17677669529663687f;  // 1/sqrt(32)
    const f32x4 zero = {};
    for (int kv = 0; kv < NPGC; kv += 32) {
        size_t kr0 = (size_t)(kv + lr) * HDIM + lg * 8;
        size_t kr1 = (size_t)(kv + 16 + lr) * HDIM + lg * 8;
        short8 kh0 = ld_frag(Kh + kr0);
        short8 kl0 = ld_frag(Kl + kr0);
        short8 kh1 = ld_frag(Kh + kr1);
        short8 kl1 = ld_frag(Kl + kr1);
        f32x4 s0 = MFMA16(ql, kh0, MFMA16(qh, kl0, MFMA16(qh, kh0, zero)));
        f32x4 s1 = MFMA16(ql, kh1, MFMA16(qh, kl1, MFMA16(qh, kh1, zero)));
#pragma unroll
        for (int r = 0; r < 4; ++r) {
            s0[r] *= scale; s1[r] *= scale;
            float mx = fmaxf(s0[r], s1[r]);
            mx = fmaxf(mx, __shfl_xor(mx, 1));
            mx = fmaxf(mx, __shfl_xor(mx, 2));
            mx = fmaxf(mx, __shfl_xor(mx, 4));
            mx = fmaxf(mx, __shfl_xor(mx, 8));
            float mn = fmaxf(m[r], mx);
            float corr = __expf(m[r] - mn);
            m[r] = mn;
            s0[r] = __expf(s0[r] - mn);
            s1[r] = __expf(s1[r] - mn);
            float ps = s0[r] + s1[r];
            ps += __shfl_xor(ps, 1);
            ps += __shfl_xor(ps, 2);
            ps += __shfl_xor(ps, 4);
            ps += __shfl_xor(ps, 8);
            l[r] = l[r] * corr + ps;
            o0[r] *= corr; o1[r] *= corr;
        }
#pragma unroll
        for (int r = 0; r < 4; ++r) {
            u16 h0, l0, h1, l1;
            fsplit(s0[r], h0, l0);
            fsplit(s1[r], h1, l1);
            plds[wave][0][lg * 4 + r][lr] = h0;
            plds[wave][0][lg * 4 + r][16 + lr] = h1;
            plds[wave][1][lg * 4 + r][lr] = l0;
            plds[wave][1][lg * 4 + r][16 + lr] = l1;
        }
        // per-wave LDS tile: in-order DS ops, no barrier needed
        short8 pfh = ld_frag(&plds[wave][0][lr][lg * 8]);
        short8 pfl = ld_frag(&plds[wave][1][lr][lg * 8]);
        size_t vr0 = (size_t)lr * NPGC + kv + lg * 8;
        size_t vr1 = (size_t)(16 + lr) * NPGC + kv + lg * 8;
        short8 vh0 = ld_frag(Vh + vr0);
        short8 vl0 = ld_frag(Vl + vr0);
        short8 vh1 = ld_frag(Vh + vr1);
        short8 vl1 = ld_frag(Vl + vr1);
        o0 = MFMA16(pfh, vh0, o0);
        o0 = MFMA16(pfl, vh0, o0);
        o0 = MFMA16(pfh, vl0, o0);
        o1 = MFMA16(pfh, vh1, o1);
        o1 = MFMA16(pfl, vh1, o1);
        o1 = MFMA16(pfh, vl1, o1);
    }
    int g = gh >> 2, hh = gh & 3;
#pragma unroll
    for (int r = 0; r < 4; ++r) {
        float inv = 1.f / l[r];
        int row = q0 + lg * 4 + r;
        size_t node = (size_t)g * NPGC + row;
        u16 h0, l0, h1, l1;
        fsplit(o0[r] * inv, h0, l0);
        fsplit(o1[r] * inv, h1, l1);
        size_t o = node * CHN + hh * HDIM + lr;
        aohi[o] = h0; aolo[o] = l0;
        aohi[o + 16] = h1; aolo[o + 16] = l1;
    }
}

// ---------------- pooling + head MLP ----------------

__global__ __launch_bounds__(128) void k_pool(const float* __restrict__ h,
                                              float* __restrict__ pool) {
    int g = blockIdx.x, c = threadIdx.x;
    const float* p = h + (size_t)g * NPGC * CHN + c;
    float s = 0.f;
    for (int i = 0; i < NPGC; ++i) s += p[(size_t)i * CHN];
    pool[g * CHN + c] = s;
}

__global__ __launch_bounds__(256) void k_head(
    const float* __restrict__ pool, const float* __restrict__ w1,
    const float* __restrict__ b1, const float* __restrict__ w2,
    const float* __restrict__ b2, const float* __restrict__ w3,
    const float* __restrict__ b3, float* __restrict__ out) {
    __shared__ float g1[16][64];
    __shared__ float g2[16][32];
    int t = threadIdx.x;
    for (int idx = t; idx < 16 * 64; idx += 256) {
        int g = idx >> 6, n = idx & 63;
        float s = b1[n];
        for (int k = 0; k < 128; ++k) s += pool[g * 128 + k] * w1[n * 128 + k];
        g1[g][n] = fmaxf(s, 0.f);
    }
    __syncthreads();
    for (int idx = t; idx < 16 * 32; idx += 256) {
        int g = idx >> 5, n = idx & 31;
        float s = b2[n];
        for (int k = 0; k < 64; ++k) s += g1[g][k] * w2[n * 64 + k];
        g2[g][n] = fmaxf(s, 0.f);
    }
    __syncthreads();
    if (t < 16) {
        float s = b3[0];
        for (int k = 0; k < 32; ++k) s += g2[t][k] * w3[k];
        out[t] = s;
    }
}

// ---------------- host ----------------

extern "C" void kernel_launch(void* const* d_in, const int* in_sizes, int n_in,
                              void* d_out, int out_size, void* d_ws, size_t ws_size,
                              hipStream_t stream) {
    (void)in_sizes; (void)n_in; (void)out_size; (void)ws_size;
    const float* x = (const float*)d_in[0];
    const float* edge_attr = (const float*)d_in[1];
    const int* edge_index = (const int*)d_in[2];
    const float* node_w = (const float*)d_in[4];
    const float* node_b = (const float*)d_in[5];
    const float* edge_w = (const float*)d_in[6];
    const float* edge_b = (const float*)d_in[7];
    const float* gine_w1 = (const float*)d_in[8];
    const float* gine_b1 = (const float*)d_in[9];
    const float* gine_w2 = (const float*)d_in[10];
    const float* gine_b2 = (const float*)d_in[11];
    const float* attn_in_w = (const float*)d_in[12];
    const float* attn_in_b = (const float*)d_in[13];
    const float* attn_out_w = (const float*)d_in[14];
    const float* attn_out_b = (const float*)d_in[15];
    const float* mlp_w1 = (const float*)d_in[16];
    const float* mlp_b1 = (const float*)d_in[17];
    const float* mlp_w2 = (const float*)d_in[18];
    const float* mlp_b2 = (const float*)d_in[19];
    const float* bn_g = (const float*)d_in[20];
    const float* bn_bb = (const float*)d_in[21];
    const float* bn_m = (const float*)d_in[22];
    const float* bn_v = (const float*)d_in[23];
    const float* head_w1 = (const float*)d_in[24];
    const float* head_b1 = (const float*)d_in[25];
    const float* head_w2 = (const float*)d_in[26];
    const float* head_b2 = (const float*)d_in[27];
    const float* head_w3 = (const float*)d_in[28];
    const float* head_b3 = (const float*)d_in[29];

    char* ws = (char*)d_ws;
    size_t off = 0;
    auto alloc = [&](size_t bytes) {
        size_t r = off;
        off = (off + bytes + 255) & ~(size_t)255;
        return r;
    };
    const size_t NC = (size_t)NODES * CHN;
    float* h_f32 = (float*)(ws + alloc(NC * 4));
    u16* h_hi = (u16*)(ws + alloc(NC * 2));
    u16* h_lo = (u16*)(ws + alloc(NC * 2));
    u16* x_hi = (u16*)(ws + alloc((size_t)NODES * 64 * 2));
    u16* x_lo = (u16*)(ws + alloc((size_t)NODES * 64 * 2));
    u16* zao_hi = (u16*)(ws + alloc(NC * 2));   // z1 / ao reuse
    u16* zao_lo = (u16*)(ws + alloc(NC * 2));
    u16* tff_hi = (u16*)(ws + alloc(NC * 2 * 2));  // t1 (first half) / ff (full)
    u16* tff_lo = (u16*)(ws + alloc(NC * 2 * 2));
    float* h1_f32 = (float*)(ws + alloc(NC * 4));
    u16* q_hi = (u16*)(ws + alloc(NC * 2));
    u16* q_lo = (u16*)(ws + alloc(NC * 2));
    u16* kk_hi = (u16*)(ws + alloc(NC * 2));
    u16* kk_lo = (u16*)(ws + alloc(NC * 2));
    u16* vt_hi = (u16*)(ws + alloc(NC * 2));
    u16* vt_lo = (u16*)(ws + alloc(NC * 2));
    float* out_f32 = (float*)(ws + alloc(NC * 4));
    u16* out_hi = (u16*)(ws + alloc(NC * 2));
    u16* out_lo = (u16*)(ws + alloc(NC * 2));
    float* pool = (float*)(ws + alloc(NG * CHN * 4));
    u16* node_w_hi = (u16*)(ws + alloc(CHN * 64 * 2));
    u16* node_w_lo = (u16*)(ws + alloc(CHN * 64 * 2));
    u16* gw1_hi = (u16*)(ws + alloc((size_t)NLAYER * CHN * CHN * 2));
    u16* gw1_lo = (u16*)(ws + alloc((size_t)NLAYER * CHN * CHN * 2));
    u16* gw2_hi = (u16*)(ws + alloc((size_t)NLAYER * CHN * CHN * 2));
    u16* gw2_lo = (u16*)(ws + alloc((size_t)NLAYER * CHN * CHN * 2));
    u16* aiw_hi = (u16*)(ws + alloc((size_t)NLAYER * 3 * CHN * CHN * 2));
    u16* aiw_lo = (u16*)(ws + alloc((size_t)NLAYER * 3 * CHN * CHN * 2));
    u16* aow_hi = (u16*)(ws + alloc((size_t)NLAYER * CHN * CHN * 2));
    u16* aow_lo = (u16*)(ws + alloc((size_t)NLAYER * CHN * CHN * 2));
    u16* mw1_hi = (u16*)(ws + alloc((size_t)NLAYER * 2 * CHN * CHN * 2));
    u16* mw1_lo = (u16*)(ws + alloc((size_t)NLAYER * 2 * CHN * CHN * 2));
    u16* mw2_hi = (u16*)(ws + alloc((size_t)NLAYER * 2 * CHN * CHN * 2));
    u16* mw2_lo = (u16*)(ws + alloc((size_t)NLAYER * 2 * CHN * CHN * 2));
    float* bn_scale = (float*)(ws + alloc(NLAYER * 3 * CHN * 4));
    float* bn_shift = (float*)(ws + alloc(NLAYER * 3 * CHN * 4));
    u32* counts = (u32*)(ws + alloc(NODES * 4));
    u32* offsets = (u32*)(ws + alloc((NODES + 1) * 4));
    u32* cursor = (u32*)(ws + alloc(NODES * 4));
    int* csr_src = (int*)(ws + alloc((size_t)NEDGE * 4));
    float* csr_a = (float*)(ws + alloc((size_t)NEDGE * 4));

    const int* e_src = edge_index;
    const int* e_dst = edge_index + NEDGE;

    auto split = [&](const float* s, u16* hi, u16* lo, int n) {
        k_split<<<dim3((n + 255) / 256), dim3(256), 0, stream>>>(s, hi, lo, n);
    };
    split(x, x_hi, x_lo, NODES * 64);
    split(node_w, node_w_hi, node_w_lo, CHN * 64);
    split(gine_w1, gw1_hi, gw1_lo, NLAYER * CHN * CHN);
    split(gine_w2, gw2_hi, gw2_lo, NLAYER * CHN * CHN);
    split(attn_in_w, aiw_hi, aiw_lo, NLAYER * 3 * CHN * CHN);
    split(attn_out_w, aow_hi, aow_lo, NLAYER * CHN * CHN);
    split(mlp_w1, mw1_hi, mw1_lo, NLAYER * 2 * CHN * CHN);
    split(mlp_w2, mw2_hi, mw2_lo, NLAYER * 2 * CHN * CHN);

    k_bnprep<<<dim3((NLAYER * 3 * CHN + 255) / 256), dim3(256), 0, stream>>>(
        bn_g, bn_bb, bn_m, bn_v, bn_scale, bn_shift);

    k_zero_u32<<<dim3(NODES / 256), dim3(256), 0, stream>>>(counts, NODES);
    k_count<<<dim3(NEDGE / 256), dim3(256), 0, stream>>>(e_dst, counts);
    k_scan<<<dim3(1), dim3(256), 0, stream>>>(counts, offsets, cursor);
    k_fill<<<dim3(NEDGE / 256), dim3(256), 0, stream>>>(e_src, e_dst, edge_attr,
                                                        cursor, csr_src, csr_a);

    auto gemm = [&](const u16* Ah, const u16* Al, const u16* Wh, const u16* Wl,
                    const float* bias, const float* r1, const float* bsc,
                    const float* bsh, const float* r2, float* of, u16* ohi,
                    u16* olo, int K, int Nc, int relu) {
        k_gemm<<<dim3(NODES / 64, Nc / 64), dim3(256), 0, stream>>>(
            Ah, Al, Wh, Wl, bias, r1, bsc, bsh, r2, of, ohi, olo, K, Nc, relu);
    };

    // node projection: h = x @ node_w^T + node_b
    gemm(x_hi, x_lo, node_w_hi, node_w_lo, node_b, nullptr, nullptr, nullptr,
         nullptr, h_f32, h_hi, h_lo, 64, CHN, 0);

    for (int l = 0; l < NLAYER; ++l) {
        size_t wo = (size_t)l * CHN * CHN;
        const float* sc0 = bn_scale + (l * 3 + 0) * CHN;
        const float* sh0 = bn_shift + (l * 3 + 0) * CHN;
        const float* sc1 = bn_scale + (l * 3 + 1) * CHN;
        const float* sh1 = bn_shift + (l * 3 + 1) * CHN;
        const float* sc2 = bn_scale + (l * 3 + 2) * CHN;
        const float* sh2 = bn_shift + (l * 3 + 2) * CHN;

        // GINE aggregate -> z (hi/lo)
        k_agg<<<dim3(NODES), dim3(64), 0, stream>>>(h_f32, offsets, csr_src,
                                                    csr_a, edge_w, edge_b,
                                                    zao_hi, zao_lo);
        // gine MLP: t1 = relu(z@w1+b1); h1 = bn(t1@w2+b2 + h)
        gemm(zao_hi, zao_lo, gw1_hi + wo, gw1_lo + wo, gine_b1 + l * CHN,
             nullptr, nullptr, nullptr, nullptr, nullptr, tff_hi, tff_lo,
             CHN, CHN, 1);
        gemm(tff_hi, tff_lo, gw2_hi + wo, gw2_lo + wo, gine_b2 + l * CHN,
             h_f32, sc0, sh0, nullptr, h1_f32, nullptr, nullptr, CHN, CHN, 0);
        // attention
        k_qkv<<<dim3(NODES / 64, 6), dim3(256), 0, stream>>>(
            h_hi, h_lo, aiw_hi + wo * 3, aiw_lo + wo * 3, attn_in_b + l * 3 * CHN,
            q_hi, q_lo, kk_hi, kk_lo, vt_hi, vt_lo);
        k_attn<<<dim3(NPGC / 64, NG * NHEAD), dim3(256), 0, stream>>>(
            q_hi, q_lo, kk_hi, kk_lo, vt_hi, vt_lo, zao_hi, zao_lo);
        // out projection: out = bn(ao@W+b + h) + h1
        gemm(zao_hi, zao_lo, aow_hi + wo, aow_lo + wo, attn_out_b + l * CHN,
             h_f32, sc1, sh1, h1_f32, out_f32, out_hi, out_lo, CHN, CHN, 0);
        // FFN: ff = relu(out@w1+b1); h = bn(ff@w2+b2 + out)
        gemm(out_hi, out_lo, mw1_hi + wo * 2, mw1_lo + wo * 2, mlp_b1 + l * 2 * CHN,
             nullptr, nullptr, nullptr, nullptr, nullptr, tff_hi, tff_lo,
             CHN, 2 * CHN, 1);
        gemm(tff_hi, tff_lo, mw2_hi + wo * 2, mw2_lo + wo * 2, mlp_b2 + l * CHN,
             out_f32, sc2, sh2, nullptr, h_f32, h_hi, h_lo, 2 * CHN, CHN, 0);
    }

    k_pool<<<dim3(NG), dim3(CHN), 0, stream>>>(h_f32, pool);
    k_head<<<dim3(1), dim3(256), 0, stream>>>(pool, head_w1, head_b1, head_w2,
                                              head_b2, head_w3, head_b3,
                                              (float*)d_out);
}

// Round 3
// 1123.922 us; speedup vs baseline: 1.0933x; 1.0933x over previous
//
#include <hip/hip_runtime.h>
#include <hip/hip_bf16.h>

typedef __attribute__((ext_vector_type(8))) short short8;
typedef __attribute__((ext_vector_type(4))) float f32x4;
typedef __attribute__((ext_vector_type(4))) unsigned int u32x4;
typedef unsigned short u16;
typedef unsigned int u32;

#define NODES 16384
#define CHN 128
#define NEDGE 524288
#define NG 16
#define NPGC 1024
#define NHEAD 4
#define HDIM 32
#define NLAYER 4

__device__ __forceinline__ float bf2f(u16 u) {
    union { u32 u; float f; } c; c.u = ((u32)u) << 16; return c.f;
}
__device__ __forceinline__ u16 f2bf(float f) {
    union { float f; u32 u; } c; c.f = f;
    u32 r = c.u + 0x7fffu + ((c.u >> 16) & 1u);
    return (u16)(r >> 16);
}
__device__ __forceinline__ void fsplit(float f, u16& hi, u16& lo) {
    u16 h = f2bf(f);
    hi = h;
    lo = f2bf(f - bf2f(h));
}
// packs bf16(a) into low 16, bf16(b) into high 16
__device__ __forceinline__ u32 cvtpk_bf16(float a, float b) {
    u32 r;
    asm("v_cvt_pk_bf16_f32 %0, %1, %2" : "=v"(r) : "v"(a), "v"(b));
    return r;
}

#define MFMA16(a, b, c) __builtin_amdgcn_mfma_f32_16x16x32_bf16((a), (b), (c), 0, 0, 0)

__device__ __forceinline__ short8 ld_frag(const u16* p) {
    return *reinterpret_cast<const short8*>(p);
}

// ---------------- setup kernels ----------------

struct SplitJobs {
    const float* src[8];
    u16* hi[8];
    u16* lo[8];
    int blk_end[8];   // cumulative block counts (each job n % 256 == 0)
};

__global__ void k_split8(SplitJobs jobs) {
    int b = blockIdx.x;
    int seg = 0;
    while (b >= jobs.blk_end[seg]) ++seg;
    int base = seg ? jobs.blk_end[seg - 1] : 0;
    int i = (b - base) * 256 + threadIdx.x;
    u16 h, l;
    fsplit(jobs.src[seg][i], h, l);
    jobs.hi[seg][i] = h;
    jobs.lo[seg][i] = l;
}

__global__ void k_bnprep(const float* __restrict__ g, const float* __restrict__ b,
                         const float* __restrict__ m, const float* __restrict__ v,
                         float* __restrict__ scale, float* __restrict__ shift) {
    int i = blockIdx.x * 256 + threadIdx.x;
    if (i < NLAYER * 3 * CHN) {
        float s = g[i] * rsqrtf(v[i] + 1e-5f);
        scale[i] = s;
        shift[i] = b[i] - m[i] * s;
    }
}

__global__ void k_zero_u32(u32* __restrict__ p, int n) {
    int i = blockIdx.x * 256 + threadIdx.x;
    if (i < n) p[i] = 0u;
}

__global__ void k_count(const int* __restrict__ dst, u32* __restrict__ counts) {
    int e = blockIdx.x * 256 + threadIdx.x;
    if (e < NEDGE) atomicAdd(&counts[dst[e]], 1u);
}

// single block, 256 threads, 64 elems each
__global__ void k_scan(const u32* __restrict__ counts, u32* __restrict__ offsets,
                       u32* __restrict__ cursor) {
    __shared__ u32 part[256];
    int t = threadIdx.x;
    int base = t * 64;
    u32 s = 0;
    for (int i = 0; i < 64; ++i) s += counts[base + i];
    part[t] = s;
    __syncthreads();
    for (int off = 1; off < 256; off <<= 1) {
        u32 val = (t >= off) ? part[t - off] : 0u;
        __syncthreads();
        part[t] += val;
        __syncthreads();
    }
    u32 run = (t == 0) ? 0u : part[t - 1];
    for (int i = 0; i < 64; ++i) {
        offsets[base + i] = run;
        cursor[base + i] = run;
        run += counts[base + i];
    }
    if (t == 255) offsets[NODES] = run;
}

__global__ void k_fill(const int* __restrict__ src, const int* __restrict__ dst,
                       const float* __restrict__ eattr, u32* __restrict__ cursor,
                       int* __restrict__ csr_src, float* __restrict__ csr_a) {
    int e = blockIdx.x * 256 + threadIdx.x;
    if (e >= NEDGE) return;
    int d = dst[e];
    u32 p = atomicAdd(&cursor[d], 1u);
    csr_src[p] = src[e];
    csr_a[p] = eattr[e];
}

// -------- GINE aggregation: z1 = h + sum_in relu(h[src] + a*ew + eb), fp32 in, hi/lo out ---

__global__ __launch_bounds__(64) void k_agg(
    const float* __restrict__ h_f32, const u32* __restrict__ offsets,
    const int* __restrict__ csr_src, const float* __restrict__ csr_a,
    const float* __restrict__ ew, const float* __restrict__ eb,
    u16* __restrict__ z_hi, u16* __restrict__ z_lo) {
    int node = blockIdx.x;
    int t = threadIdx.x;          // 64 threads, 2 channels each
    int c0 = t * 2;
    float w0 = ew[c0], w1 = ew[c0 + 1];
    float b0 = eb[c0], b1 = eb[c0 + 1];
    u32 beg = offsets[node], end = offsets[node + 1];
    float acc0 = 0.f, acc1 = 0.f;
    for (u32 j = beg; j < end; ++j) {
        int s = csr_src[j];
        float a = csr_a[j];
        const float* hp = h_f32 + (size_t)s * CHN + c0;
        float f0 = hp[0], f1 = hp[1];
        acc0 += fmaxf(f0 + a * w0 + b0, 0.f);
        acc1 += fmaxf(f1 + a * w1 + b1, 0.f);
    }
    size_t idx = (size_t)node * CHN + c0;
    float z0 = h_f32[idx] + acc0;
    float z1v = h_f32[idx + 1] + acc1;
    u16 h, l;
    fsplit(z0, h, l); z_hi[idx] = h; z_lo[idx] = l;
    fsplit(z1v, h, l); z_hi[idx + 1] = h; z_lo[idx + 1] = l;
}

// ------ split GEMM: acc = (Ah+Al)@(Wh+Wl)^T; epi: +bias; +resid1; *bn+; +resid2; relu ------

__global__ __launch_bounds__(256) void k_gemm(
    const u16* __restrict__ Ahi, const u16* __restrict__ Alo,
    const u16* __restrict__ Whi, const u16* __restrict__ Wlo,
    const float* __restrict__ bias, const float* __restrict__ resid1,
    const float* __restrict__ bnscale, const float* __restrict__ bnshift,
    const float* __restrict__ resid2, float* __restrict__ out_f32,
    u16* __restrict__ out_hi, u16* __restrict__ out_lo, int K, int Nc, int relu) {
    int tid = threadIdx.x;
    int wave = tid >> 6, lane = tid & 63;
    int lr = lane & 15, lg = lane >> 4;
    int r0 = blockIdx.x * 64 + wave * 16;
    int nb = blockIdx.y * 64;
    f32x4 acc[4] = {};
    size_t arow = (size_t)(r0 + lr) * K + lg * 8;
    for (int ks = 0; ks < K; ks += 32) {
        short8 ah = ld_frag(Ahi + arow + ks);
        short8 al = ld_frag(Alo + arow + ks);
#pragma unroll
        for (int n = 0; n < 4; ++n) {
            size_t wrow = (size_t)(nb + n * 16 + lr) * K + ks + lg * 8;
            short8 wh = ld_frag(Whi + wrow);
            short8 wl = ld_frag(Wlo + wrow);
            acc[n] = MFMA16(ah, wh, acc[n]);
            acc[n] = MFMA16(al, wh, acc[n]);
            acc[n] = MFMA16(ah, wl, acc[n]);
        }
    }
#pragma unroll
    for (int n = 0; n < 4; ++n) {
        int col = nb + n * 16 + lr;
        float bs = bias ? bias[col] : 0.f;
        float sc = bnscale ? bnscale[col] : 1.f;
        float sh = bnshift ? bnshift[col] : 0.f;
#pragma unroll
        for (int r = 0; r < 4; ++r) {
            int row = r0 + lg * 4 + r;
            size_t oidx = (size_t)row * Nc + col;
            float v = acc[n][r] + bs;
            if (resid1) v += resid1[oidx];
            v = v * sc + sh;
            if (resid2) v += resid2[oidx];
            if (relu) v = fmaxf(v, 0.f);
            if (out_f32) out_f32[oidx] = v;
            if (out_hi) {
                u16 hh, ll;
                fsplit(v, hh, ll);
                out_hi[oidx] = hh; out_lo[oidx] = ll;
            }
        }
    }
}

// -------- QKV GEMM with head-split hi/lo store (V transposed, hi-only, pi-permuted) --------

__global__ __launch_bounds__(256) void k_qkv(
    const u16* __restrict__ Ahi, const u16* __restrict__ Alo,
    const u16* __restrict__ Whi, const u16* __restrict__ Wlo,
    const float* __restrict__ bias,
    u16* __restrict__ q_hi, u16* __restrict__ q_lo,
    u16* __restrict__ k_hi, u16* __restrict__ k_lo,
    u16* __restrict__ vt_hi) {
    const int K = 128;
    int tid = threadIdx.x;
    int wave = tid >> 6, lane = tid & 63;
    int lr = lane & 15, lg = lane >> 4;
    int r0 = blockIdx.x * 64 + wave * 16;
    int nb = blockIdx.y * 64;    // grid.y = 6 -> 384 cols
    f32x4 acc[4] = {};
    size_t arow = (size_t)(r0 + lr) * K + lg * 8;
    for (int ks = 0; ks < K; ks += 32) {
        short8 ah = ld_frag(Ahi + arow + ks);
        short8 al = ld_frag(Alo + arow + ks);
#pragma unroll
        for (int n = 0; n < 4; ++n) {
            size_t wrow = (size_t)(nb + n * 16 + lr) * K + ks + lg * 8;
            short8 wh = ld_frag(Whi + wrow);
            short8 wl = ld_frag(Wlo + wrow);
            acc[n] = MFMA16(ah, wh, acc[n]);
            acc[n] = MFMA16(al, wh, acc[n]);
            acc[n] = MFMA16(ah, wl, acc[n]);
        }
    }
#pragma unroll
    for (int n = 0; n < 4; ++n) {
        int col = nb + n * 16 + lr;
        int region = col >> 7;
        int c = col & 127;
        int hh = c >> 5, d = c & 31;
        float bs = bias[col];
#pragma unroll
        for (int r = 0; r < 4; ++r) {
            int row = r0 + lg * 4 + r;
            float v = acc[n][r] + bs;
            int g = row >> 10, p = row & 1023;
            size_t gh = (size_t)(g * NHEAD + hh);
            if (region == 0) {
                u16 vh, vl;
                fsplit(v, vh, vl);
                size_t o = (gh * NPGC + p) * HDIM + d;
                q_hi[o] = vh; q_lo[o] = vl;
            } else if (region == 1) {
                u16 vh, vl;
                fsplit(v, vh, vl);
                size_t o = (gh * NPGC + p) * HDIM + d;
                k_hi[o] = vh; k_lo[o] = vl;
            } else {
                // pi-permute key index within its 128-block: pp = (p&15)*8 + (p&127)/16
                int pp = (p & ~127) | (((p & 15) << 3) | ((p & 127) >> 4));
                vt_hi[(gh * HDIM + d) * NPGC + pp] = f2bf(v);
            }
        }
    }
}

// --- flash attention: 4 waves/block, 16 q-rows/wave, KV chunk=128, split QK / bf16 PV ---

#define KVB 128
#define PLDS_STRIDE 136   // u16 units; 272B rows keep ds_*_b128 16B-aligned

__global__ __launch_bounds__(256) void k_attn(
    const u16* __restrict__ qhi, const u16* __restrict__ qlo,
    const u16* __restrict__ khi, const u16* __restrict__ klo,
    const u16* __restrict__ vthi,
    u16* __restrict__ aohi, u16* __restrict__ aolo) {
    __shared__ __align__(16) u16 plds[4][16][PLDS_STRIDE];
    int tid = threadIdx.x;
    int wave = tid >> 6, lane = tid & 63;
    int lr = lane & 15, lg = lane >> 4;
    int gh = blockIdx.y;                       // g*4 + head
    int q0 = blockIdx.x * 64 + wave * 16;      // row within NPG
    size_t qbase = (size_t)gh * NPGC * HDIM;
    size_t vbase = (size_t)gh * HDIM * NPGC;
    short8 qh = ld_frag(qhi + qbase + (size_t)(q0 + lr) * HDIM + lg * 8);
    short8 ql = ld_frag(qlo + qbase + (size_t)(q0 + lr) * HDIM + lg * 8);
    const u16* Kh = khi + qbase;
    const u16* Kl = klo + qbase;
    const u16* Vh = vthi + vbase;
    f32x4 o0 = {}, o1 = {};
    float m[4], l[4];
#pragma unroll
    for (int r = 0; r < 4; ++r) { m[r] = -1e30f; l[r] = 0.f; }
    // cl = log2(e)/sqrt(HDIM): softmax over raw scores via exp2((s - m)*cl)
    const float cl = 0.2550348281f;
    const f32x4 zero = {};
    for (int kv = 0; kv < NPGC; kv += KVB) {
        f32x4 s[8];
#pragma unroll
        for (int f = 0; f < 8; ++f) {
            size_t kr = (size_t)(kv + f * 16 + lr) * HDIM + lg * 8;
            short8 kh = ld_frag(Kh + kr);
            short8 kl = ld_frag(Kl + kr);
            s[f] = MFMA16(ql, kh, MFMA16(qh, kl, MFMA16(qh, kh, zero)));
        }
#pragma unroll
        for (int r = 0; r < 4; ++r) {
            // in-lane max over 8 frags (tree), then 4 shuffle rounds over lr lanes
            float m01 = fmaxf(s[0][r], s[1][r]);
            float m23 = fmaxf(s[2][r], s[3][r]);
            float m45 = fmaxf(s[4][r], s[5][r]);
            float m67 = fmaxf(s[6][r], s[7][r]);
            float mx = fmaxf(fmaxf(m01, m23), fmaxf(m45, m67));
            mx = fmaxf(mx, __shfl_xor(mx, 1));
            mx = fmaxf(mx, __shfl_xor(mx, 2));
            mx = fmaxf(mx, __shfl_xor(mx, 4));
            mx = fmaxf(mx, __shfl_xor(mx, 8));
            float mn = fmaxf(m[r], mx);
            float mncl = mn * cl;
            float corr = exp2f(m[r] * cl - mncl);
            m[r] = mn;
            float e[8];
#pragma unroll
            for (int f = 0; f < 8; ++f) e[f] = exp2f(fmaf(s[f][r], cl, -mncl));
            float ps = ((e[0] + e[1]) + (e[2] + e[3])) + ((e[4] + e[5]) + (e[6] + e[7]));
            ps += __shfl_xor(ps, 1);
            ps += __shfl_xor(ps, 2);
            ps += __shfl_xor(ps, 4);
            ps += __shfl_xor(ps, 8);
            l[r] = fmaf(l[r], corr, ps);
            o0[r] *= corr; o1[r] *= corr;
            // pack P row (pi-order: lane's 8 cols are contiguous at 8*lr) -> 1 b128 write
            u32x4 pw;
            pw[0] = cvtpk_bf16(e[0], e[1]);
            pw[1] = cvtpk_bf16(e[2], e[3]);
            pw[2] = cvtpk_bf16(e[4], e[5]);
            pw[3] = cvtpk_bf16(e[6], e[7]);
            *reinterpret_cast<u32x4*>(&plds[wave][lg * 4 + r][lr * 8]) = pw;
        }
        // PV: A = P (bf16 hi), B = V^T rows in pi order (stored that way by k_qkv)
#pragma unroll
        for (int kk = 0; kk < 4; ++kk) {
            short8 pf = ld_frag(&plds[wave][lr][kk * 32 + lg * 8]);
            size_t vr = kv + kk * 32 + lg * 8;
            short8 vh0 = ld_frag(Vh + (size_t)lr * NPGC + vr);
            short8 vh1 = ld_frag(Vh + (size_t)(16 + lr) * NPGC + vr);
            o0 = MFMA16(pf, vh0, o0);
            o1 = MFMA16(pf, vh1, o1);
        }
    }
    int g = gh >> 2, hh = gh & 3;
#pragma unroll
    for (int r = 0; r < 4; ++r) {
        float inv = 1.f / l[r];
        int row = q0 + lg * 4 + r;
        size_t node = (size_t)g * NPGC + row;
        u16 h0, l0, h1, l1;
        fsplit(o0[r] * inv, h0, l0);
        fsplit(o1[r] * inv, h1, l1);
        size_t o = node * CHN + hh * HDIM + lr;
        aohi[o] = h0; aolo[o] = l0;
        aohi[o + 16] = h1; aolo[o + 16] = l1;
    }
}

// ---------------- pooling + head MLP ----------------

__global__ __launch_bounds__(128) void k_pool(const float* __restrict__ h,
                                              float* __restrict__ pool) {
    int g = blockIdx.x, c = threadIdx.x;
    const float* p = h + (size_t)g * NPGC * CHN + c;
    float s = 0.f;
    for (int i = 0; i < NPGC; ++i) s += p[(size_t)i * CHN];
    pool[g * CHN + c] = s;
}

__global__ __launch_bounds__(256) void k_head(
    const float* __restrict__ pool, const float* __restrict__ w1,
    const float* __restrict__ b1, const float* __restrict__ w2,
    const float* __restrict__ b2, const float* __restrict__ w3,
    const float* __restrict__ b3, float* __restrict__ out) {
    __shared__ float g1[16][64];
    __shared__ float g2[16][32];
    int t = threadIdx.x;
    for (int idx = t; idx < 16 * 64; idx += 256) {
        int g = idx >> 6, n = idx & 63;
        float s = b1[n];
        for (int k = 0; k < 128; ++k) s += pool[g * 128 + k] * w1[n * 128 + k];
        g1[g][n] = fmaxf(s, 0.f);
    }
    __syncthreads();
    for (int idx = t; idx < 16 * 32; idx += 256) {
        int g = idx >> 5, n = idx & 31;
        float s = b2[n];
        for (int k = 0; k < 64; ++k) s += g1[g][k] * w2[n * 64 + k];
        g2[g][n] = fmaxf(s, 0.f);
    }
    __syncthreads();
    if (t < 16) {
        float s = b3[0];
        for (int k = 0; k < 32; ++k) s += g2[t][k] * w3[k];
        out[t] = s;
    }
}

// ---------------- host ----------------

extern "C" void kernel_launch(void* const* d_in, const int* in_sizes, int n_in,
                              void* d_out, int out_size, void* d_ws, size_t ws_size,
                              hipStream_t stream) {
    (void)in_sizes; (void)n_in; (void)out_size; (void)ws_size;
    const float* x = (const float*)d_in[0];
    const float* edge_attr = (const float*)d_in[1];
    const int* edge_index = (const int*)d_in[2];
    const float* node_w = (const float*)d_in[4];
    const float* node_b = (const float*)d_in[5];
    const float* edge_w = (const float*)d_in[6];
    const float* edge_b = (const float*)d_in[7];
    const float* gine_w1 = (const float*)d_in[8];
    const float* gine_b1 = (const float*)d_in[9];
    const float* gine_w2 = (const float*)d_in[10];
    const float* gine_b2 = (const float*)d_in[11];
    const float* attn_in_w = (const float*)d_in[12];
    const float* attn_in_b = (const float*)d_in[13];
    const float* attn_out_w = (const float*)d_in[14];
    const float* attn_out_b = (const float*)d_in[15];
    const float* mlp_w1 = (const float*)d_in[16];
    const float* mlp_b1 = (const float*)d_in[17];
    const float* mlp_w2 = (const float*)d_in[18];
    const float* mlp_b2 = (const float*)d_in[19];
    const float* bn_g = (const float*)d_in[20];
    const float* bn_bb = (const float*)d_in[21];
    const float* bn_m = (const float*)d_in[22];
    const float* bn_v = (const float*)d_in[23];
    const float* head_w1 = (const float*)d_in[24];
    const float* head_b1 = (const float*)d_in[25];
    const float* head_w2 = (const float*)d_in[26];
    const float* head_b2 = (const float*)d_in[27];
    const float* head_w3 = (const float*)d_in[28];
    const float* head_b3 = (const float*)d_in[29];

    char* ws = (char*)d_ws;
    size_t off = 0;
    auto alloc = [&](size_t bytes) {
        size_t r = off;
        off = (off + bytes + 255) & ~(size_t)255;
        return r;
    };
    const size_t NC = (size_t)NODES * CHN;
    float* h_f32 = (float*)(ws + alloc(NC * 4));
    u16* h_hi = (u16*)(ws + alloc(NC * 2));
    u16* h_lo = (u16*)(ws + alloc(NC * 2));
    u16* x_hi = (u16*)(ws + alloc((size_t)NODES * 64 * 2));
    u16* x_lo = (u16*)(ws + alloc((size_t)NODES * 64 * 2));
    u16* zao_hi = (u16*)(ws + alloc(NC * 2));   // z1 / ao reuse
    u16* zao_lo = (u16*)(ws + alloc(NC * 2));
    u16* tff_hi = (u16*)(ws + alloc(NC * 2 * 2));  // t1 (first half) / ff (full)
    u16* tff_lo = (u16*)(ws + alloc(NC * 2 * 2));
    float* h1_f32 = (float*)(ws + alloc(NC * 4));
    u16* q_hi = (u16*)(ws + alloc(NC * 2));
    u16* q_lo = (u16*)(ws + alloc(NC * 2));
    u16* kk_hi = (u16*)(ws + alloc(NC * 2));
    u16* kk_lo = (u16*)(ws + alloc(NC * 2));
    u16* vt_hi = (u16*)(ws + alloc(NC * 2));
    float* out_f32 = (float*)(ws + alloc(NC * 4));
    u16* out_hi = (u16*)(ws + alloc(NC * 2));
    u16* out_lo = (u16*)(ws + alloc(NC * 2));
    float* pool = (float*)(ws + alloc(NG * CHN * 4));
    u16* node_w_hi = (u16*)(ws + alloc(CHN * 64 * 2));
    u16* node_w_lo = (u16*)(ws + alloc(CHN * 64 * 2));
    u16* gw1_hi = (u16*)(ws + alloc((size_t)NLAYER * CHN * CHN * 2));
    u16* gw1_lo = (u16*)(ws + alloc((size_t)NLAYER * CHN * CHN * 2));
    u16* gw2_hi = (u16*)(ws + alloc((size_t)NLAYER * CHN * CHN * 2));
    u16* gw2_lo = (u16*)(ws + alloc((size_t)NLAYER * CHN * CHN * 2));
    u16* aiw_hi = (u16*)(ws + alloc((size_t)NLAYER * 3 * CHN * CHN * 2));
    u16* aiw_lo = (u16*)(ws + alloc((size_t)NLAYER * 3 * CHN * CHN * 2));
    u16* aow_hi = (u16*)(ws + alloc((size_t)NLAYER * CHN * CHN * 2));
    u16* aow_lo = (u16*)(ws + alloc((size_t)NLAYER * CHN * CHN * 2));
    u16* mw1_hi = (u16*)(ws + alloc((size_t)NLAYER * 2 * CHN * CHN * 2));
    u16* mw1_lo = (u16*)(ws + alloc((size_t)NLAYER * 2 * CHN * CHN * 2));
    u16* mw2_hi = (u16*)(ws + alloc((size_t)NLAYER * 2 * CHN * CHN * 2));
    u16* mw2_lo = (u16*)(ws + alloc((size_t)NLAYER * 2 * CHN * CHN * 2));
    float* bn_scale = (float*)(ws + alloc(NLAYER * 3 * CHN * 4));
    float* bn_shift = (float*)(ws + alloc(NLAYER * 3 * CHN * 4));
    u32* counts = (u32*)(ws + alloc(NODES * 4));
    u32* offsets = (u32*)(ws + alloc((NODES + 1) * 4));
    u32* cursor = (u32*)(ws + alloc(NODES * 4));
    int* csr_src = (int*)(ws + alloc((size_t)NEDGE * 4));
    float* csr_a = (float*)(ws + alloc((size_t)NEDGE * 4));

    const int* e_src = edge_index;
    const int* e_dst = edge_index + NEDGE;

    // one fused split launch for all 8 fp32->hi/lo conversions
    {
        SplitJobs j;
        const float* srcs[8] = {x, node_w, gine_w1, gine_w2, attn_in_w,
                                attn_out_w, mlp_w1, mlp_w2};
        u16* his[8] = {x_hi, node_w_hi, gw1_hi, gw2_hi, aiw_hi, aow_hi, mw1_hi, mw2_hi};
        u16* los[8] = {x_lo, node_w_lo, gw1_lo, gw2_lo, aiw_lo, aow_lo, mw1_lo, mw2_lo};
        int ns[8] = {NODES * 64, CHN * 64, NLAYER * CHN * CHN, NLAYER * CHN * CHN,
                     NLAYER * 3 * CHN * CHN, NLAYER * CHN * CHN,
                     NLAYER * 2 * CHN * CHN, NLAYER * 2 * CHN * CHN};
        int cum = 0;
        for (int i = 0; i < 8; ++i) {
            j.src[i] = srcs[i]; j.hi[i] = his[i]; j.lo[i] = los[i];
            cum += ns[i] / 256;
            j.blk_end[i] = cum;
        }
        k_split8<<<dim3(cum), dim3(256), 0, stream>>>(j);
    }

    k_bnprep<<<dim3((NLAYER * 3 * CHN + 255) / 256), dim3(256), 0, stream>>>(
        bn_g, bn_bb, bn_m, bn_v, bn_scale, bn_shift);

    k_zero_u32<<<dim3(NODES / 256), dim3(256), 0, stream>>>(counts, NODES);
    k_count<<<dim3(NEDGE / 256), dim3(256), 0, stream>>>(e_dst, counts);
    k_scan<<<dim3(1), dim3(256), 0, stream>>>(counts, offsets, cursor);
    k_fill<<<dim3(NEDGE / 256), dim3(256), 0, stream>>>(e_src, e_dst, edge_attr,
                                                        cursor, csr_src, csr_a);

    auto gemm = [&](const u16* Ah, const u16* Al, const u16* Wh, const u16* Wl,
                    const float* bias, const float* r1, const float* bsc,
                    const float* bsh, const float* r2, float* of, u16* ohi,
                    u16* olo, int K, int Nc, int relu) {
        k_gemm<<<dim3(NODES / 64, Nc / 64), dim3(256), 0, stream>>>(
            Ah, Al, Wh, Wl, bias, r1, bsc, bsh, r2, of, ohi, olo, K, Nc, relu);
    };

    // node projection: h = x @ node_w^T + node_b
    gemm(x_hi, x_lo, node_w_hi, node_w_lo, node_b, nullptr, nullptr, nullptr,
         nullptr, h_f32, h_hi, h_lo, 64, CHN, 0);

    for (int l = 0; l < NLAYER; ++l) {
        size_t wo = (size_t)l * CHN * CHN;
        const float* sc0 = bn_scale + (l * 3 + 0) * CHN;
        const float* sh0 = bn_shift + (l * 3 + 0) * CHN;
        const float* sc1 = bn_scale + (l * 3 + 1) * CHN;
        const float* sh1 = bn_shift + (l * 3 + 1) * CHN;
        const float* sc2 = bn_scale + (l * 3 + 2) * CHN;
        const float* sh2 = bn_shift + (l * 3 + 2) * CHN;

        // GINE aggregate -> z (hi/lo)
        k_agg<<<dim3(NODES), dim3(64), 0, stream>>>(h_f32, offsets, csr_src,
                                                    csr_a, edge_w, edge_b,
                                                    zao_hi, zao_lo);
        // gine MLP: t1 = relu(z@w1+b1); h1 = bn(t1@w2+b2 + h)
        gemm(zao_hi, zao_lo, gw1_hi + wo, gw1_lo + wo, gine_b1 + l * CHN,
             nullptr, nullptr, nullptr, nullptr, nullptr, tff_hi, tff_lo,
             CHN, CHN, 1);
        gemm(tff_hi, tff_lo, gw2_hi + wo, gw2_lo + wo, gine_b2 + l * CHN,
             h_f32, sc0, sh0, nullptr, h1_f32, nullptr, nullptr, CHN, CHN, 0);
        // attention
        k_qkv<<<dim3(NODES / 64, 6), dim3(256), 0, stream>>>(
            h_hi, h_lo, aiw_hi + wo * 3, aiw_lo + wo * 3, attn_in_b + l * 3 * CHN,
            q_hi, q_lo, kk_hi, kk_lo, vt_hi);
        k_attn<<<dim3(NPGC / 64, NG * NHEAD), dim3(256), 0, stream>>>(
            q_hi, q_lo, kk_hi, kk_lo, vt_hi, zao_hi, zao_lo);
        // out projection: out = bn(ao@W+b + h) + h1
        gemm(zao_hi, zao_lo, aow_hi + wo, aow_lo + wo, attn_out_b + l * CHN,
             h_f32, sc1, sh1, h1_f32, out_f32, out_hi, out_lo, CHN, CHN, 0);
        // FFN: ff = relu(out@w1+b1); h = bn(ff@w2+b2 + out)
        gemm(out_hi, out_lo, mw1_hi + wo * 2, mw1_lo + wo * 2, mlp_b1 + l * 2 * CHN,
             nullptr, nullptr, nullptr, nullptr, nullptr, tff_hi, tff_lo,
             CHN, 2 * CHN, 1);
        gemm(tff_hi, tff_lo, mw2_hi + wo * 2, mw2_lo + wo * 2, mlp_b2 + l * CHN,
             out_f32, sc2, sh2, nullptr, h_f32, h_hi, h_lo, 2 * CHN, CHN, 0);
    }

    k_pool<<<dim3(NG), dim3(CHN), 0, stream>>>(h_f32, pool);
    k_head<<<dim3(1), dim3(256), 0, stream>>>(pool, head_w1, head_b1, head_w2,
                                              head_b2, head_w3, head_b3,
                                              (float*)d_out);
}